// Round 3
// baseline (292.984 us; speedup 1.0000x reference)
//
#include <hip/hip_runtime.h>
#include <math.h>

// ---------------------------------------------------------------------------
// out = DHT2_128( crop_center_128( DHT2_256(x) ) ), x: (512, 256, 256) fp32.
// Two-kernel structure (proven). This revision splits stage1 into one block
// per (image, v-half): PQt LDS halves to 64 KiB -> 2 blocks/CU -> 16 waves/CU.
// stage2 is byte-identical to the proven 276us version.
//
// ws layout (bf16 elements):
//   W1t [256][256] at 0      : row j<128 -> cas(2pi (64+j) m /256) (P cols)
//                              row j>=128 -> cas(2pi (320-j) m /256) (Q cols)
//   W2  [128][512] at 65536  : [u][k] k<256 -> cos(2pi (64+u) k /256)
//                                      k>=256 -> sin(2pi (64+u)(k-256)/256)
//   W3t [256][128] at 131072 : 128-point analog of W1t (mult j / 256-j)
//   W4  [128][256] at 163840 : 128-point analog of W2
// ---------------------------------------------------------------------------

typedef __attribute__((ext_vector_type(8))) short bfrag;   // 8 bf16 (4 VGPRs)
typedef __attribute__((ext_vector_type(4))) float ffrag;   // 4 fp32 acc

#define PI2_256 0.0245436926061702597f
#define PI2_128 0.0490873852123405194f

__device__ __forceinline__ unsigned short f2bf(float f) {
    union { float f; unsigned int u; } v; v.f = f;
    unsigned int r = v.u + 0x7fffu + ((v.u >> 16) & 1u);
    return (unsigned short)(r >> 16);
}

__device__ __forceinline__ bfrag pack8(float4 a, float4 b) {
    bfrag r;
    r[0] = (short)f2bf(a.x); r[1] = (short)f2bf(a.y);
    r[2] = (short)f2bf(a.z); r[3] = (short)f2bf(a.w);
    r[4] = (short)f2bf(b.x); r[5] = (short)f2bf(b.y);
    r[6] = (short)f2bf(b.z); r[7] = (short)f2bf(b.w);
    return r;
}

// ---------------------------------------------------------------------------
__global__ __launch_bounds__(256) void gen_tables(unsigned short* __restrict__ ws)
{
    const int id = blockIdx.x * 256 + threadIdx.x;   // 65536 threads
    // W1t [256][256]
    {
        const int j = id >> 8, m = id & 255;
        const int mult = (j < 128) ? (64 + j) : (320 - j);
        const int idx = (mult * m) & 255;
        float s, c; sincosf((float)idx * PI2_256, &s, &c);
        ws[id] = f2bf(c + s);
    }
    // W2 [128][512]
    {
        const int u = id >> 9, k = id & 511;
        const int up = 64 + u;
        float s, c, val;
        if (k < 256) { sincosf((float)((up * k) & 255) * PI2_256, &s, &c); val = c; }
        else         { sincosf((float)((up * (k - 256)) & 255) * PI2_256, &s, &c); val = s; }
        ws[65536 + id] = f2bf(val);
    }
    if (id < 32768) {
        // W3t [256][128]
        {
            const int j = id >> 7, m = id & 127;
            const int mult = (j < 128) ? j : (256 - j);
            const int idx = (mult * m) & 127;
            float s, c; sincosf((float)idx * PI2_128, &s, &c);
            ws[131072 + id] = f2bf(c + s);
        }
        // W4 [128][256]
        {
            const int u = id >> 8, k = id & 255;
            float s, c, val;
            if (k < 128) { sincosf((float)((u * k) & 127) * PI2_128, &s, &c); val = c; }
            else         { sincosf((float)((u * (k - 128)) & 127) * PI2_128, &s, &c); val = s; }
            ws[163840 + id] = f2bf(val);
        }
    }
}

// ---------------------------------------------------------------------------
// Stage 1: one block per (image, v-half). 512 threads (8 waves), 64 KiB LDS
// -> 2 blocks/CU, 16 waves/CU.
//   Phase A: C[n][c] = sum_m X[n][m] * W1t[c][m] for the 128 c-columns whose
//            v = c&127 lies in [64h, 64h+64)  -> PQt LDS (swizzled)
//   Phase B: Dc[u][64h+vl] = sum_k W2[u][k] * PQt[vl][k]  -> d_out fp32
// ---------------------------------------------------------------------------
__global__ __launch_bounds__(512, 4) void stage1(const float* __restrict__ X,
                                                 const unsigned short* __restrict__ ws,
                                                 float* __restrict__ dc)
{
    __shared__ unsigned short PQt[64 * 512];   // 64 KiB, XOR-swizzled (granule = 8 bf16)

    const int t  = threadIdx.x;
    const int w  = t >> 6;          // wave 0..7
    const int ln = t & 15;          // lane & 15
    const int q  = (t & 63) >> 4;   // quad 0..3
    const int img = blockIdx.x >> 1;
    const int h   = blockIdx.x & 1;  // v-half: block handles v in [64h, 64h+64)

    const float* __restrict__ Xi = X + (size_t)img * 65536;
    const unsigned short* __restrict__ W1 = ws;            // [256][256]
    const unsigned short* __restrict__ W2 = ws + 65536;    // [128][512]

    // ---- Phase A ----
    {
        ffrag acc[2][8];
#pragma unroll
        for (int mt = 0; mt < 2; ++mt)
#pragma unroll
            for (int nt = 0; nt < 8; ++nt)
                acc[mt][nt] = (ffrag){0.f, 0.f, 0.f, 0.f};

        const int rowA0 = 32 * w;
        for (int kk = 0; kk < 8; ++kk) {
            const int k = kk * 32 + q * 8;
            bfrag A[2];
#pragma unroll
            for (int mt = 0; mt < 2; ++mt) {
                const float* xp = Xi + (size_t)(rowA0 + 16 * mt + ln) * 256 + k;
                const float4 x0 = *(const float4*)xp;
                const float4 x1 = *(const float4*)(xp + 4);
                A[mt] = pack8(x0, x1);
            }
#pragma unroll
            for (int nt = 0; nt < 8; ++nt) {
                // c-columns: nt<4 -> P half [64h, 64h+64); nt>=4 -> Q half [128+64h, ...)
                const int c = 64 * h + ((nt & 3) * 16 + ln) + ((nt >= 4) ? 128 : 0);
                const bfrag B = *(const bfrag*)(W1 + c * 256 + k);
#pragma unroll
                for (int mt = 0; mt < 2; ++mt)
                    acc[mt][nt] = __builtin_amdgcn_mfma_f32_16x16x32_bf16(A[mt], B, acc[mt][nt], 0, 0, 0);
            }
        }
        // Store to swizzled PQt: lane's 4 regs are 4 consecutive n (k2 dim).
#pragma unroll
        for (int mt = 0; mt < 2; ++mt) {
#pragma unroll
            for (int nt = 0; nt < 8; ++nt) {
                const int vl = (nt & 3) * 16 + ln;                       // [0,64)
                const int kb = ((nt >= 4) ? 256 : 0) + rowA0 + 16 * mt + 4 * q;
                const unsigned int lo = (unsigned int)f2bf(acc[mt][nt][0]) |
                                        ((unsigned int)f2bf(acc[mt][nt][1]) << 16);
                const unsigned int hi = (unsigned int)f2bf(acc[mt][nt][2]) |
                                        ((unsigned int)f2bf(acc[mt][nt][3]) << 16);
                const int phys = vl * 512 + (((kb >> 3) ^ (vl & 7)) << 3) + (kb & 7);
                *(uint2*)&PQt[phys] = make_uint2(lo, hi);
            }
        }
    }
    __syncthreads();

    // ---- Phase B ----
    {
        ffrag acc[4];
#pragma unroll
        for (int nt = 0; nt < 4; ++nt) acc[nt] = (ffrag){0.f, 0.f, 0.f, 0.f};

        const int u0 = 16 * w;                  // u-tile, [0,128)
        for (int kk = 0; kk < 16; ++kk) {
            const int k = kk * 32 + q * 8;
            const bfrag A = *(const bfrag*)(W2 + (size_t)(u0 + ln) * 512 + k);
#pragma unroll
            for (int nt = 0; nt < 4; ++nt) {
                const int vl = nt * 16 + ln;
                const int g = (k >> 3) ^ (vl & 7);
                const bfrag B = *(const bfrag*)&PQt[vl * 512 + (g << 3)];
                acc[nt] = __builtin_amdgcn_mfma_f32_16x16x32_bf16(A, B, acc[nt], 0, 0, 0);
            }
        }
        float* __restrict__ D = dc + (size_t)img * 16384;
#pragma unroll
        for (int nt = 0; nt < 4; ++nt) {
#pragma unroll
            for (int r = 0; r < 4; ++r) {
                const int u = u0 + 4 * q + r;
                const int v = 64 * h + nt * 16 + ln;
                D[u * 128 + v] = acc[nt][r];
            }
        }
    }
}

// ---------------------------------------------------------------------------
// Stage 2: one block per image, 256 threads (4 waves). Dc buffered in LDS
// (bf16, swizzled) BEFORE any output store -> no cross-image race.
//   Phase A2: C3[p][c] = sum_m Dcb[p][m] * W3t[jsel(c)][m]  (128x128x128)
//   Phase B2: Out[u][64*vh+v] = sum_k W4[u][k] * PQ2[v][k]  (128x64x256)
// (byte-identical to the proven 276us version)
// ---------------------------------------------------------------------------
__global__ __launch_bounds__(256, 2) void stage2(const unsigned short* __restrict__ ws,
                                                 float* __restrict__ io)
{
    __shared__ unsigned short Dcb[128 * 128];   // 32 KiB swizzled [p][m]
    __shared__ unsigned short PQ2[64 * 256];    // 32 KiB swizzled [v][k]

    const int t  = threadIdx.x;
    const int w  = t >> 6;          // wave 0..3
    const int ln = t & 15;
    const int q  = (t & 63) >> 4;
    const int img = blockIdx.x;

    float* __restrict__ G = io + (size_t)img * 16384;
    const unsigned short* __restrict__ W3 = ws + 131072;   // [256][128]
    const unsigned short* __restrict__ W4 = ws + 163840;   // [128][256]

    // Load Dc fp32 -> Dcb bf16 (swizzled).
    {
        const int p = t >> 1, half = t & 1;
        const float* src = G + p * 128 + half * 64;
#pragma unroll
        for (int g = 0; g < 8; ++g) {
            const float4 a = *(const float4*)(src + g * 8);
            const float4 b = *(const float4*)(src + g * 8 + 4);
            const int m0 = half * 64 + g * 8;
            const int gran = (m0 >> 3) ^ (p & 7);
            uint4 val;
            val.x = (unsigned int)f2bf(a.x) | ((unsigned int)f2bf(a.y) << 16);
            val.y = (unsigned int)f2bf(a.z) | ((unsigned int)f2bf(a.w) << 16);
            val.z = (unsigned int)f2bf(b.x) | ((unsigned int)f2bf(b.y) << 16);
            val.w = (unsigned int)f2bf(b.z) | ((unsigned int)f2bf(b.w) << 16);
            *(uint4*)&Dcb[p * 128 + gran * 8] = val;
        }
    }
    __syncthreads();

    for (int vh = 0; vh < 2; ++vh) {
        // ---- Phase A2 ----
        ffrag acc[2][8];
#pragma unroll
        for (int mt = 0; mt < 2; ++mt)
#pragma unroll
            for (int nt = 0; nt < 8; ++nt)
                acc[mt][nt] = (ffrag){0.f, 0.f, 0.f, 0.f};

        const int p0 = 32 * w;
        for (int kk = 0; kk < 4; ++kk) {
            const int k = kk * 32 + q * 8;
            bfrag A[2];
#pragma unroll
            for (int mt = 0; mt < 2; ++mt) {
                const int p = p0 + 16 * mt + ln;
                const int g = (k >> 3) ^ (p & 7);
                A[mt] = *(const bfrag*)&Dcb[p * 128 + g * 8];
            }
#pragma unroll
            for (int nt = 0; nt < 8; ++nt) {
                const int c = nt * 16 + ln;
                const int j = (c < 64) ? (64 * vh + c) : (128 + 64 * vh + (c - 64));
                const bfrag B = *(const bfrag*)(W3 + j * 128 + k);
#pragma unroll
                for (int mt = 0; mt < 2; ++mt)
                    acc[mt][nt] = __builtin_amdgcn_mfma_f32_16x16x32_bf16(A[mt], B, acc[mt][nt], 0, 0, 0);
            }
        }
        __syncthreads();   // vh=1: previous B2 must finish reading PQ2
#pragma unroll
        for (int mt = 0; mt < 2; ++mt) {
#pragma unroll
            for (int nt = 0; nt < 8; ++nt) {
                const int c  = nt * 16 + ln;
                const int v  = c & 63;
                const int kb = ((c < 64) ? 0 : 128) + p0 + 16 * mt + 4 * q;
                const unsigned int lo = (unsigned int)f2bf(acc[mt][nt][0]) |
                                        ((unsigned int)f2bf(acc[mt][nt][1]) << 16);
                const unsigned int hi = (unsigned int)f2bf(acc[mt][nt][2]) |
                                        ((unsigned int)f2bf(acc[mt][nt][3]) << 16);
                const int phys = v * 256 + ((((kb >> 3) ^ (v & 7)) << 3)) + (kb & 7);
                *(uint2*)&PQ2[phys] = make_uint2(lo, hi);
            }
        }
        __syncthreads();

        // ---- Phase B2 ----
        ffrag o[2][4];
#pragma unroll
        for (int mt = 0; mt < 2; ++mt)
#pragma unroll
            for (int nt = 0; nt < 4; ++nt)
                o[mt][nt] = (ffrag){0.f, 0.f, 0.f, 0.f};

        const int u0 = 32 * w;
        for (int kk = 0; kk < 8; ++kk) {
            const int k = kk * 32 + q * 8;
            bfrag A[2];
#pragma unroll
            for (int mt = 0; mt < 2; ++mt)
                A[mt] = *(const bfrag*)(W4 + (size_t)(u0 + 16 * mt + ln) * 256 + k);
#pragma unroll
            for (int nt = 0; nt < 4; ++nt) {
                const int v = nt * 16 + ln;
                const int g = (k >> 3) ^ (v & 7);
                const bfrag B = *(const bfrag*)&PQ2[v * 256 + (g << 3)];
#pragma unroll
                for (int mt = 0; mt < 2; ++mt)
                    o[mt][nt] = __builtin_amdgcn_mfma_f32_16x16x32_bf16(A[mt], B, o[mt][nt], 0, 0, 0);
            }
        }
#pragma unroll
        for (int mt = 0; mt < 2; ++mt) {
#pragma unroll
            for (int nt = 0; nt < 4; ++nt) {
#pragma unroll
                for (int r = 0; r < 4; ++r) {
                    const int u = u0 + 16 * mt + 4 * q + r;
                    const int v = 64 * vh + nt * 16 + ln;
                    G[u * 128 + v] = o[mt][nt][r];
                }
            }
        }
    }
}

// ---------------------------------------------------------------------------
extern "C" void kernel_launch(void* const* d_in, const int* in_sizes, int n_in,
                              void* d_out, int out_size, void* d_ws, size_t ws_size,
                              hipStream_t stream)
{
    const float* x = (const float*)d_in[0];
    float* out = (float*)d_out;
    unsigned short* tw = (unsigned short*)d_ws;   // needs 393,216 bytes

    gen_tables<<<dim3(256), dim3(256), 0, stream>>>(tw);
    stage1<<<dim3(1024), dim3(512), 0, stream>>>(x, tw, out);
    stage2<<<dim3(512), dim3(256), 0, stream>>>(tw, out);
}

// Round 5
// 279.088 us; speedup vs baseline: 1.0498x; 1.0498x over previous
//
#include <hip/hip_runtime.h>
#include <math.h>

// ---------------------------------------------------------------------------
// out = DHT2_128( crop_center_128( DHT2_256(x) ) ), x: (512, 256, 256) fp32.
//
// Batched-GEMM formulation (4 passes over the whole batch, chunked by image
// group G if ws_size is small). All passes are the same BT-GEMM pattern:
//   P1: C_t[img][c][n]  = sum_m X[img][n][m]   * W1t[c][m]   (transposed store)
//   P2: Dc[img][u][v]   = sum_k W2[u][k]       * A2[v][k]    A2 = C_t rows v / v+128
//   P3: C3_t[img][jj][p]= sum_m Dc[img][p][m]  * W3t[jj][m]  (transposed store)
//   P4: Out[img][u][v]  = sum_k W4[u][k]       * A4[v][k]    A4 = C3_t rows v / v+128
// B tables staged in XOR-swizzled LDS once per block; A streams from global.
//
// ws layout: tables (bf16, 393216 B) at 0; then regionA (C_t, reused for C3_t)
// then regionDc. Fallback to the proven two-kernel per-image path if ws_size
// is too small (< 557056 B).
// ---------------------------------------------------------------------------

typedef __attribute__((ext_vector_type(8))) short bfrag;   // 8 bf16 (4 VGPRs)
typedef __attribute__((ext_vector_type(4))) float ffrag;   // 4 fp32 acc

#define PI2_256 0.0245436926061702597f
#define PI2_128 0.0490873852123405194f

__device__ __forceinline__ unsigned short f2bf(float f) {
    union { float f; unsigned int u; } v; v.f = f;
    unsigned int r = v.u + 0x7fffu + ((v.u >> 16) & 1u);
    return (unsigned short)(r >> 16);
}

__device__ __forceinline__ bfrag pack8(float4 a, float4 b) {
    bfrag r;
    r[0] = (short)f2bf(a.x); r[1] = (short)f2bf(a.y);
    r[2] = (short)f2bf(a.z); r[3] = (short)f2bf(a.w);
    r[4] = (short)f2bf(b.x); r[5] = (short)f2bf(b.y);
    r[6] = (short)f2bf(b.z); r[7] = (short)f2bf(b.w);
    return r;
}

__device__ __forceinline__ uint2 packlohi(ffrag a) {
    uint2 r;
    r.x = (unsigned int)f2bf(a[0]) | ((unsigned int)f2bf(a[1]) << 16);
    r.y = (unsigned int)f2bf(a[2]) | ((unsigned int)f2bf(a[3]) << 16);
    return r;
}

// Stage a row-major [NCOLS][K] bf16 table into LDS with granule-8 XOR swizzle.
template<int NCOLS, int K>
__device__ __forceinline__ void stageB(const unsigned short* __restrict__ src,
                                       unsigned short* __restrict__ Lb, int t)
{
    constexpr int CHUNKS = NCOLS * K / 8;   // 16B chunks
#pragma unroll
    for (int i = 0; i < CHUNKS / 512; ++i) {
        const int o = (t + i * 512) * 8;
        const int j = o / K;
        const int k = o - j * K;
        const uint4 v = *(const uint4*)(src + o);
        *(uint4*)&Lb[j * K + (((k >> 3) ^ (j & 7)) << 3)] = v;
    }
}

template<int K>
__device__ __forceinline__ bfrag ldsB(const unsigned short* __restrict__ Lb, int j, int k)
{
    return *(const bfrag*)&Lb[j * K + (((k >> 3) ^ (j & 7)) << 3)];
}

// ---------------------------------------------------------------------------
__global__ __launch_bounds__(256) void gen_tables(unsigned short* __restrict__ ws)
{
    const int id = blockIdx.x * 256 + threadIdx.x;   // 65536 threads
    // W1t [256][256]
    {
        const int j = id >> 8, m = id & 255;
        const int mult = (j < 128) ? (64 + j) : (320 - j);
        const int idx = (mult * m) & 255;
        float s, c; sincosf((float)idx * PI2_256, &s, &c);
        ws[id] = f2bf(c + s);
    }
    // W2 [128][512]
    {
        const int u = id >> 9, k = id & 511;
        const int up = 64 + u;
        float s, c, val;
        if (k < 256) { sincosf((float)((up * k) & 255) * PI2_256, &s, &c); val = c; }
        else         { sincosf((float)((up * (k - 256)) & 255) * PI2_256, &s, &c); val = s; }
        ws[65536 + id] = f2bf(val);
    }
    if (id < 32768) {
        // W3t [256][128]
        {
            const int j = id >> 7, m = id & 127;
            const int mult = (j < 128) ? j : (256 - j);
            const int idx = (mult * m) & 127;
            float s, c; sincosf((float)idx * PI2_128, &s, &c);
            ws[131072 + id] = f2bf(c + s);
        }
        // W4 [128][256]
        {
            const int u = id >> 8, k = id & 255;
            float s, c, val;
            if (k < 128) { sincosf((float)((u * k) & 127) * PI2_128, &s, &c); val = c; }
            else         { sincosf((float)((u * (k - 128)) & 127) * PI2_128, &s, &c); val = s; }
            ws[163840 + id] = f2bf(val);
        }
    }
}

// ---------------------------------------------------------------------------
// Pass 1: C_t[img][c][n] = sum_m X[img][n][m] * W1t[c][m]
// grid: 2G blocks (128 rows each), 512 threads.
// ---------------------------------------------------------------------------
__global__ __launch_bounds__(512, 2) void pass1(const float* __restrict__ X,
                                                const unsigned short* __restrict__ ws,
                                                unsigned short* __restrict__ Ct)
{
    __shared__ unsigned short Lb[256 * 256];   // 128 KiB: W1t swizzled

    const int t  = threadIdx.x;
    const int w  = t >> 6;
    const int ln = t & 15;
    const int q  = (t & 63) >> 4;

    stageB<256, 256>(ws, Lb, t);
    __syncthreads();

    const int img = blockIdx.x >> 1;
    const int nb  = (blockIdx.x & 1) * 128;    // n-half of the image
    const float* __restrict__ Ar = X + (size_t)img * 65536 + (size_t)(nb + 16 * w + ln) * 256;

    ffrag acc[16];
#pragma unroll
    for (int nt = 0; nt < 16; ++nt) acc[nt] = (ffrag){0.f, 0.f, 0.f, 0.f};

    for (int kk = 0; kk < 8; ++kk) {
        const int k = kk * 32 + q * 8;
        const float4 x0 = *(const float4*)(Ar + k);
        const float4 x1 = *(const float4*)(Ar + k + 4);
        const bfrag A = pack8(x0, x1);
#pragma unroll
        for (int nt = 0; nt < 16; ++nt) {
            const bfrag B = ldsB<256>(Lb, nt * 16 + ln, k);
            acc[nt] = __builtin_amdgcn_mfma_f32_16x16x32_bf16(A, B, acc[nt], 0, 0, 0);
        }
    }
    // Transposed store: row n = nb+16w+4q+r (4 consecutive), col c = nt*16+ln.
    unsigned short* __restrict__ Co = Ct + (size_t)img * 65536 + nb + 16 * w + 4 * q;
#pragma unroll
    for (int nt = 0; nt < 16; ++nt) {
        *(uint2*)&Co[(size_t)(nt * 16 + ln) * 256] = packlohi(acc[nt]);
    }
}

// ---------------------------------------------------------------------------
// Pass 2: Dc[img][u][v] = sum_{kh,k} W2[u][kh*256+k] * C_t[img][v+kh*128][k]
// grid: G blocks (one image each), 512 threads.
// ---------------------------------------------------------------------------
__global__ __launch_bounds__(512, 2) void pass2(const unsigned short* __restrict__ Ct,
                                                const unsigned short* __restrict__ ws,
                                                unsigned short* __restrict__ Dc)
{
    __shared__ unsigned short Lb[128 * 512];   // 128 KiB: W2 swizzled

    const int t  = threadIdx.x;
    const int w  = t >> 6;
    const int ln = t & 15;
    const int q  = (t & 63) >> 4;

    stageB<128, 512>(ws + 65536, Lb, t);
    __syncthreads();

    const int img = blockIdx.x;
    const unsigned short* __restrict__ Abase = Ct + (size_t)img * 65536;
    const int v = 16 * w + ln;

    ffrag acc[8];
#pragma unroll
    for (int nt = 0; nt < 8; ++nt) acc[nt] = (ffrag){0.f, 0.f, 0.f, 0.f};

#pragma unroll
    for (int kh = 0; kh < 2; ++kh) {
        const unsigned short* __restrict__ Ar = Abase + (size_t)(v + kh * 128) * 256;
        for (int kk = 0; kk < 8; ++kk) {
            const int k = kk * 32 + q * 8;
            const bfrag A = *(const bfrag*)(Ar + k);
            const int kfull = kh * 256 + k;
#pragma unroll
            for (int nt = 0; nt < 8; ++nt) {
                const bfrag B = ldsB<512>(Lb, nt * 16 + ln, kfull);
                acc[nt] = __builtin_amdgcn_mfma_f32_16x16x32_bf16(A, B, acc[nt], 0, 0, 0);
            }
        }
    }
    // Store Dc[img][u][v']: u = nt*16+ln, v' = 16w+4q+r (consecutive).
    unsigned short* __restrict__ Do = Dc + (size_t)img * 16384 + 16 * w + 4 * q;
#pragma unroll
    for (int nt = 0; nt < 8; ++nt) {
        *(uint2*)&Do[(size_t)(nt * 16 + ln) * 128] = packlohi(acc[nt]);
    }
}

// ---------------------------------------------------------------------------
// Pass 3: C3_t[img][jj][p] = sum_m Dc[img][p][m] * W3t[jj][m]
// grid: G blocks, 512 threads.
// ---------------------------------------------------------------------------
__global__ __launch_bounds__(512, 2) void pass3(const unsigned short* __restrict__ Dc,
                                                const unsigned short* __restrict__ ws,
                                                unsigned short* __restrict__ C3t)
{
    __shared__ unsigned short Lb[256 * 128];   // 64 KiB: W3t swizzled

    const int t  = threadIdx.x;
    const int w  = t >> 6;
    const int ln = t & 15;
    const int q  = (t & 63) >> 4;

    stageB<256, 128>(ws + 131072, Lb, t);
    __syncthreads();

    const int img = blockIdx.x;
    const unsigned short* __restrict__ Ar = Dc + (size_t)img * 16384 + (size_t)(16 * w + ln) * 128;

    ffrag acc[16];
#pragma unroll
    for (int nt = 0; nt < 16; ++nt) acc[nt] = (ffrag){0.f, 0.f, 0.f, 0.f};

    for (int kk = 0; kk < 4; ++kk) {
        const int k = kk * 32 + q * 8;
        const bfrag A = *(const bfrag*)(Ar + k);
#pragma unroll
        for (int nt = 0; nt < 16; ++nt) {
            const bfrag B = ldsB<128>(Lb, nt * 16 + ln, k);
            acc[nt] = __builtin_amdgcn_mfma_f32_16x16x32_bf16(A, B, acc[nt], 0, 0, 0);
        }
    }
    // Transposed store: C3_t[img][jj][p'], p' = 16w+4q+r.
    unsigned short* __restrict__ Co = C3t + (size_t)img * 32768 + 16 * w + 4 * q;
#pragma unroll
    for (int nt = 0; nt < 16; ++nt) {
        *(uint2*)&Co[(size_t)(nt * 16 + ln) * 128] = packlohi(acc[nt]);
    }
}

// ---------------------------------------------------------------------------
// Pass 4: Out[img][u][v] = sum_{kh,k} W4[u][kh*128+k] * C3_t[img][v+kh*128][k]
// grid: G blocks, 512 threads. fp32 output.
// ---------------------------------------------------------------------------
__global__ __launch_bounds__(512, 2) void pass4(const unsigned short* __restrict__ C3t,
                                                const unsigned short* __restrict__ ws,
                                                float* __restrict__ out)
{
    __shared__ unsigned short Lb[128 * 256];   // 64 KiB: W4 swizzled

    const int t  = threadIdx.x;
    const int w  = t >> 6;
    const int ln = t & 15;
    const int q  = (t & 63) >> 4;

    stageB<128, 256>(ws + 163840, Lb, t);
    __syncthreads();

    const int img = blockIdx.x;
    const unsigned short* __restrict__ Abase = C3t + (size_t)img * 32768;
    const int v = 16 * w + ln;

    ffrag acc[8];
#pragma unroll
    for (int nt = 0; nt < 8; ++nt) acc[nt] = (ffrag){0.f, 0.f, 0.f, 0.f};

#pragma unroll
    for (int kh = 0; kh < 2; ++kh) {
        const unsigned short* __restrict__ Ar = Abase + (size_t)(v + kh * 128) * 128;
        for (int kk = 0; kk < 4; ++kk) {
            const int k = kk * 32 + q * 8;
            const bfrag A = *(const bfrag*)(Ar + k);
            const int kfull = kh * 128 + k;
#pragma unroll
            for (int nt = 0; nt < 8; ++nt) {
                const bfrag B = ldsB<256>(Lb, nt * 16 + ln, kfull);
                acc[nt] = __builtin_amdgcn_mfma_f32_16x16x32_bf16(A, B, acc[nt], 0, 0, 0);
            }
        }
    }
    // Store fp32: Out[img][u][v'], u = nt*16+ln, v' = 16w+4q+r (float4).
    float* __restrict__ G = out + (size_t)img * 16384 + 16 * w + 4 * q;
#pragma unroll
    for (int nt = 0; nt < 8; ++nt) {
        float4 o4 = make_float4(acc[nt][0], acc[nt][1], acc[nt][2], acc[nt][3]);
        *(float4*)&G[(size_t)(nt * 16 + ln) * 128] = o4;
    }
}

// ---------------------------------------------------------------------------
// Fallback path (ws too small): the proven per-image two-kernel version.
// ---------------------------------------------------------------------------
__global__ __launch_bounds__(512, 2) void stage1_old(const float* __restrict__ X,
                                                     const unsigned short* __restrict__ ws,
                                                     float* __restrict__ dc)
{
    __shared__ unsigned short PQt[128 * 512];

    const int t  = threadIdx.x;
    const int w  = t >> 6;
    const int ln = t & 15;
    const int q  = (t & 63) >> 4;
    const int img = blockIdx.x;

    const float* __restrict__ Xi = X + (size_t)img * 65536;
    const unsigned short* __restrict__ W1 = ws;
    const unsigned short* __restrict__ W2 = ws + 65536;

    {
        ffrag acc[2][16];
#pragma unroll
        for (int mt = 0; mt < 2; ++mt)
#pragma unroll
            for (int nt = 0; nt < 16; ++nt)
                acc[mt][nt] = (ffrag){0.f, 0.f, 0.f, 0.f};

        const int rowA0 = 32 * w;
        for (int kk = 0; kk < 8; ++kk) {
            const int k = kk * 32 + q * 8;
            bfrag A[2];
#pragma unroll
            for (int mt = 0; mt < 2; ++mt) {
                const float* xp = Xi + (size_t)(rowA0 + 16 * mt + ln) * 256 + k;
                const float4 x0 = *(const float4*)xp;
                const float4 x1 = *(const float4*)(xp + 4);
                A[mt] = pack8(x0, x1);
            }
#pragma unroll
            for (int nt = 0; nt < 16; ++nt) {
                const int j = nt * 16 + ln;
                const bfrag B = *(const bfrag*)(W1 + j * 256 + k);
#pragma unroll
                for (int mt = 0; mt < 2; ++mt)
                    acc[mt][nt] = __builtin_amdgcn_mfma_f32_16x16x32_bf16(A[mt], B, acc[mt][nt], 0, 0, 0);
            }
        }
#pragma unroll
        for (int mt = 0; mt < 2; ++mt) {
#pragma unroll
            for (int nt = 0; nt < 16; ++nt) {
                const int c  = nt * 16 + ln;
                const int v  = c & 127;
                const int kb = ((c < 128) ? 0 : 256) + rowA0 + 16 * mt + 4 * q;
                const uint2 lohi = packlohi(acc[mt][nt]);
                const int phys = v * 512 + (((kb >> 3) ^ (v & 7)) << 3) + (kb & 7);
                *(uint2*)&PQt[phys] = lohi;
            }
        }
    }
    __syncthreads();

    {
        ffrag acc[8];
#pragma unroll
        for (int nt = 0; nt < 8; ++nt) acc[nt] = (ffrag){0.f, 0.f, 0.f, 0.f};

        const int u0 = 16 * w;
        for (int kk = 0; kk < 16; ++kk) {
            const int k = kk * 32 + q * 8;
            const bfrag A = *(const bfrag*)(W2 + (size_t)(u0 + ln) * 512 + k);
#pragma unroll
            for (int nt = 0; nt < 8; ++nt) {
                const int v = nt * 16 + ln;
                const int g = (k >> 3) ^ (v & 7);
                const bfrag B = *(const bfrag*)&PQt[v * 512 + (g << 3)];
                acc[nt] = __builtin_amdgcn_mfma_f32_16x16x32_bf16(A, B, acc[nt], 0, 0, 0);
            }
        }
        float* __restrict__ D = dc + (size_t)img * 16384;
#pragma unroll
        for (int nt = 0; nt < 8; ++nt) {
#pragma unroll
            for (int r = 0; r < 4; ++r) {
                const int u = u0 + 4 * q + r;
                const int v = nt * 16 + ln;
                D[u * 128 + v] = acc[nt][r];
            }
        }
    }
}

__global__ __launch_bounds__(256, 2) void stage2_old(const unsigned short* __restrict__ ws,
                                                     float* __restrict__ io)
{
    __shared__ unsigned short Dcb[128 * 128];
    __shared__ unsigned short PQ2[64 * 256];

    const int t  = threadIdx.x;
    const int w  = t >> 6;
    const int ln = t & 15;
    const int q  = (t & 63) >> 4;
    const int img = blockIdx.x;

    float* __restrict__ G = io + (size_t)img * 16384;
    const unsigned short* __restrict__ W3 = ws + 131072;
    const unsigned short* __restrict__ W4 = ws + 163840;

    {
        const int p = t >> 1, half = t & 1;
        const float* src = G + p * 128 + half * 64;
#pragma unroll
        for (int g = 0; g < 8; ++g) {
            const float4 a = *(const float4*)(src + g * 8);
            const float4 b = *(const float4*)(src + g * 8 + 4);
            const int m0 = half * 64 + g * 8;
            const int gran = (m0 >> 3) ^ (p & 7);
            uint4 val;
            val.x = (unsigned int)f2bf(a.x) | ((unsigned int)f2bf(a.y) << 16);
            val.y = (unsigned int)f2bf(a.z) | ((unsigned int)f2bf(a.w) << 16);
            val.z = (unsigned int)f2bf(b.x) | ((unsigned int)f2bf(b.y) << 16);
            val.w = (unsigned int)f2bf(b.z) | ((unsigned int)f2bf(b.w) << 16);
            *(uint4*)&Dcb[p * 128 + gran * 8] = val;
        }
    }
    __syncthreads();

    for (int vh = 0; vh < 2; ++vh) {
        ffrag acc[2][8];
#pragma unroll
        for (int mt = 0; mt < 2; ++mt)
#pragma unroll
            for (int nt = 0; nt < 8; ++nt)
                acc[mt][nt] = (ffrag){0.f, 0.f, 0.f, 0.f};

        const int p0 = 32 * w;
        for (int kk = 0; kk < 4; ++kk) {
            const int k = kk * 32 + q * 8;
            bfrag A[2];
#pragma unroll
            for (int mt = 0; mt < 2; ++mt) {
                const int p = p0 + 16 * mt + ln;
                const int g = (k >> 3) ^ (p & 7);
                A[mt] = *(const bfrag*)&Dcb[p * 128 + g * 8];
            }
#pragma unroll
            for (int nt = 0; nt < 8; ++nt) {
                const int c = nt * 16 + ln;
                const int j = (c < 64) ? (64 * vh + c) : (128 + 64 * vh + (c - 64));
                const bfrag B = *(const bfrag*)(W3 + j * 128 + k);
#pragma unroll
                for (int mt = 0; mt < 2; ++mt)
                    acc[mt][nt] = __builtin_amdgcn_mfma_f32_16x16x32_bf16(A[mt], B, acc[mt][nt], 0, 0, 0);
            }
        }
        __syncthreads();
#pragma unroll
        for (int mt = 0; mt < 2; ++mt) {
#pragma unroll
            for (int nt = 0; nt < 8; ++nt) {
                const int c  = nt * 16 + ln;
                const int v  = c & 63;
                const int kb = ((c < 64) ? 0 : 128) + p0 + 16 * mt + 4 * q;
                const uint2 lohi = packlohi(acc[mt][nt]);
                const int phys = v * 256 + (((kb >> 3) ^ (v & 7)) << 3) + (kb & 7);
                *(uint2*)&PQ2[phys] = lohi;
            }
        }
        __syncthreads();

        ffrag o[2][4];
#pragma unroll
        for (int mt = 0; mt < 2; ++mt)
#pragma unroll
            for (int nt = 0; nt < 4; ++nt)
                o[mt][nt] = (ffrag){0.f, 0.f, 0.f, 0.f};

        const int u0 = 32 * w;
        for (int kk = 0; kk < 8; ++kk) {
            const int k = kk * 32 + q * 8;
            bfrag A[2];
#pragma unroll
            for (int mt = 0; mt < 2; ++mt)
                A[mt] = *(const bfrag*)(W4 + (size_t)(u0 + 16 * mt + ln) * 256 + k);
#pragma unroll
            for (int nt = 0; nt < 4; ++nt) {
                const int v = nt * 16 + ln;
                const int g = (k >> 3) ^ (v & 7);
                const bfrag B = *(const bfrag*)&PQ2[v * 256 + (g << 3)];
#pragma unroll
                for (int mt = 0; mt < 2; ++mt)
                    o[mt][nt] = __builtin_amdgcn_mfma_f32_16x16x32_bf16(A[mt], B, o[mt][nt], 0, 0, 0);
            }
        }
#pragma unroll
        for (int mt = 0; mt < 2; ++mt) {
#pragma unroll
            for (int nt = 0; nt < 4; ++nt) {
#pragma unroll
                for (int r = 0; r < 4; ++r) {
                    const int u = u0 + 16 * mt + 4 * q + r;
                    const int v = 64 * vh + nt * 16 + ln;
                    G[u * 128 + v] = o[mt][nt][r];
                }
            }
        }
    }
}

// ---------------------------------------------------------------------------
extern "C" void kernel_launch(void* const* d_in, const int* in_sizes, int n_in,
                              void* d_out, int out_size, void* d_ws, size_t ws_size,
                              hipStream_t stream)
{
    const float* x = (const float*)d_in[0];
    float* out = (float*)d_out;
    unsigned short* tw = (unsigned short*)d_ws;

    gen_tables<<<dim3(256), dim3(256), 0, stream>>>(tw);

    // Per-chunk workspace need (bytes): tables 393216 + regionA (C_t, 2*65536*G)
    // + regionDc (2*16384*G) = 393216 + 163840*G.
    int G = 512;
    while (G > 1 && (size_t)163840 * (size_t)G + 393216 > ws_size) G >>= 1;

    if ((size_t)163840 * (size_t)G + 393216 <= ws_size) {
        unsigned short* regA  = tw + 196608;                 // byte off 393216
        unsigned short* regDc = regA + (size_t)G * 65536;
        const int nchunks = 512 / G;
        for (int ci = 0; ci < nchunks; ++ci) {
            const float* xc = x + (size_t)ci * G * 65536;
            float* oc = out + (size_t)ci * G * 16384;
            pass1<<<dim3(2 * G), dim3(512), 0, stream>>>(xc, tw, regA);
            pass2<<<dim3(G), dim3(512), 0, stream>>>(regA, tw, regDc);
            pass3<<<dim3(G), dim3(512), 0, stream>>>(regDc, tw, regA);
            pass4<<<dim3(G), dim3(512), 0, stream>>>(regA, tw, oc);
        }
    } else {
        // ws too small for the batched path: proven per-image fallback.
        stage1_old<<<dim3(512), dim3(512), 0, stream>>>(x, tw, out);
        stage2_old<<<dim3(512), dim3(256), 0, stream>>>(tw, out);
    }
}